// Round 5
// baseline (445.668 us; speedup 1.0000x reference)
//
#include <hip/hip_runtime.h>
#include <stdint.h>

typedef short short8 __attribute__((ext_vector_type(8)));
typedef float f32x16 __attribute__((ext_vector_type(16)));
typedef float fx4 __attribute__((ext_vector_type(4)));
typedef unsigned ux4 __attribute__((ext_vector_type(4)));

__device__ __forceinline__ unsigned cvtpk(float lo, float hi){
  unsigned r;
  asm("v_cvt_pk_bf16_f32 %0, %1, %2" : "=v"(r) : "v"(lo), "v"(hi));
  return r;
}

__device__ __forceinline__ short8 frag_from(unsigned a, unsigned b, unsigned c, unsigned d){
  union { unsigned u[4]; short8 s; } t;
  t.u[0] = a; t.u[1] = b; t.u[2] = c; t.u[3] = d;
  return t.s;
}

// ---------------- prep: pack W1^T / W2^T into MFMA A-fragment order ----------------
__global__ void k_prep(const float* __restrict__ W1, const float* __restrict__ W2,
                       ux4* __restrict__ Wf)
{
  const int t = blockIdx.x * 256 + threadIdx.x;
  if (t >= 48 * 64) return;
  const int f = t >> 6, l = t & 63;
  const int r = l & 31, hh = l >> 5;
  float v[8];
  if (f < 16) {
    const int mf = f >> 2, ks = f & 3;
    const int c = 32 * mf + r, kb = ks * 16 + hh * 8;
#pragma unroll
    for (int j = 0; j < 8; ++j) v[j] = W1[(kb + j) * 128 + c];
  } else {
    const int f2 = f - 16, mf2 = f2 >> 3, ks = f2 & 7;
    const int o = 32 * mf2 + r, cb = ks * 16 + hh * 8;
#pragma unroll
    for (int j = 0; j < 8; ++j) v[j] = W2[(cb + j) * 128 + o];
  }
  ux4 d;
  d.x = cvtpk(v[0], v[1]); d.y = cvtpk(v[2], v[3]);
  d.z = cvtpk(v[4], v[5]); d.w = cvtpk(v[6], v[7]);
  Wf[(long long)f * 64 + l] = d;
}

// ---------------- CSR build ----------------
__global__ void k_hist(const int* __restrict__ ei, int* __restrict__ rowptr, int E){
  for (long long i = (long long)blockIdx.x * 256 + threadIdx.x; i < E;
       i += (long long)gridDim.x * 256)
    atomicAdd(&rowptr[ei[E + i]], 1);
}

__global__ __launch_bounds__(1024)
void k_scan(int* __restrict__ p, int N){
  __shared__ int ls[1024];
  const int t = threadIdx.x;
  const int chunk = (N + 1023) >> 10;
  const int c0 = t * chunk, c1 = min(N, c0 + chunk);
  int s = 0;
  for (int i = c0; i < c1; ++i) s += p[i];
  ls[t] = s;
  __syncthreads();
  for (int off = 1; off < 1024; off <<= 1) {
    int add = (t >= off) ? ls[t - off] : 0;
    __syncthreads();
    ls[t] += add;
    __syncthreads();
  }
  int run = (t == 0) ? 0 : ls[t - 1];
  for (int i = c0; i < c1; ++i) { int v = p[i]; p[i] = run; run += v; }
}

__global__ void k_fill(const int* __restrict__ ei, int* __restrict__ rowptr,
                       int* __restrict__ pose, int E){
  for (long long i = (long long)blockIdx.x * 256 + threadIdx.x; i < E;
       i += (long long)gridDim.x * 256) {
    int tg = ei[E + i];
    pose[i] = atomicAdd(&rowptr[tg], 1);
  }
}

// ---------------- K1: fused normalize + MLP (MFMA) + messages + scores ----------------
__global__ __launch_bounds__(256, 5)
void k1_fused(const float* __restrict__ x, const int* __restrict__ ei,
              const float* __restrict__ ea, const ux4* __restrict__ Wf,
              const float* __restrict__ b1, const float* __restrict__ b2,
              const float* __restrict__ attn, const int* __restrict__ pose,
              unsigned* __restrict__ msgp, float* __restrict__ scoreS,
              float* __restrict__ scorig, int E)
{
  const int lane = threadIdx.x & 63;
  const int wv   = threadIdx.x >> 6;
  const int h    = lane >> 5;
  const int r31  = lane & 31;
  const long long e   = (long long)blockIdx.x * 128 + wv * 32 + r31;
  const long long eld = (e < E) ? e : (long long)(E - 1);

  const int pos = pose[eld];
  const int src = ei[eld];
  const float* xrow = x + (long long)src * 128;

  // ---- load edge_attr (streamed, nontemporal), convert to bf16 UNNORMALIZED,
  //      accumulate sum of squares; normalization folded into acc1 scale.
  const fx4* earow = (const fx4*)(ea + eld * 64 + h * 8);
  float ss = 0.f;
  unsigned eb[4][4];
#pragma unroll
  for (int ks = 0; ks < 4; ++ks) {
    fx4 p0 = __builtin_nontemporal_load(earow + ks * 4);
    fx4 p1 = __builtin_nontemporal_load(earow + ks * 4 + 1);
    ss = fmaf(p0.x, p0.x, ss); ss = fmaf(p0.y, p0.y, ss);
    ss = fmaf(p0.z, p0.z, ss); ss = fmaf(p0.w, p0.w, ss);
    ss = fmaf(p1.x, p1.x, ss); ss = fmaf(p1.y, p1.y, ss);
    ss = fmaf(p1.z, p1.z, ss); ss = fmaf(p1.w, p1.w, ss);
    eb[ks][0] = cvtpk(p0.x, p0.y); eb[ks][1] = cvtpk(p0.z, p0.w);
    eb[ks][2] = cvtpk(p1.x, p1.y); eb[ks][3] = cvtpk(p1.z, p1.w);
  }
  ss += __shfl_xor(ss, 32);
  const float rin = 1.0f / (sqrtf(ss) + 1e-8f);   // per-edge = per-lane-column scale

  // ---- L1 (staged per mf): h = tanh((ean_un @ W1)*rin + b1), B-fragments in-register ----
  unsigned hb[8][4];
#pragma unroll
  for (int mf = 0; mf < 4; ++mf) {
    f32x16 a1;
#pragma unroll
    for (int i = 0; i < 16; ++i) a1[i] = 0.f;
#pragma unroll
    for (int ks = 0; ks < 4; ++ks) {
      ux4 w = Wf[(mf * 4 + ks) * 64 + lane];
      a1 = __builtin_amdgcn_mfma_f32_32x32x16_bf16(
          frag_from(w.x, w.y, w.z, w.w),
          frag_from(eb[ks][0], eb[ks][1], eb[ks][2], eb[ks][3]), a1, 0, 0, 0);
    }
    float hv[16];
#pragma unroll
    for (int rq = 0; rq < 4; ++rq) {
      float4 bc = *(const float4*)(b1 + 32*mf + 8*rq + 4*h);
#pragma unroll
      for (int i = 0; i < 4; ++i) {
        float pre = fmaf(a1[rq*4+i], rin, ((const float*)&bc)[i]);
        float e2  = __expf(2.0f * pre);
        hv[rq*4+i] = 1.0f - 2.0f / (e2 + 1.0f);
      }
    }
#pragma unroll
    for (int q = 0; q < 2; ++q) {
      unsigned A = cvtpk(hv[q*8+0], hv[q*8+1]);
      unsigned B = cvtpk(hv[q*8+2], hv[q*8+3]);
      unsigned C = cvtpk(hv[q*8+4], hv[q*8+5]);
      unsigned D = cvtpk(hv[q*8+6], hv[q*8+7]);
      unsigned Axr = (unsigned)__shfl_xor((int)A, 32);
      unsigned Bxr = (unsigned)__shfl_xor((int)B, 32);
      unsigned Cxr = (unsigned)__shfl_xor((int)C, 32);
      unsigned Dxr = (unsigned)__shfl_xor((int)D, 32);
      hb[2*mf+q][0] = h ? Cxr : A;
      hb[2*mf+q][1] = h ? Dxr : B;
      hb[2*mf+q][2] = h ? C   : Axr;
      hb[2*mf+q][3] = h ? D   : Bxr;
    }
  }

  // ---- L2 (staged per mf2) + epilogue; x chunk loaded per-mf2 at use ----
  float score = 0.f;
#pragma unroll
  for (int mf2 = 0; mf2 < 4; ++mf2) {
    float4 xq[4];
#pragma unroll
    for (int rq = 0; rq < 4; ++rq)
      xq[rq] = *(const float4*)(xrow + 32*mf2 + 8*rq + 4*h);

    f32x16 a2;
#pragma unroll
    for (int i = 0; i < 16; ++i) a2[i] = 0.f;
#pragma unroll
    for (int ks = 0; ks < 8; ++ks) {
      ux4 w = Wf[(16 + mf2 * 8 + ks) * 64 + lane];
      a2 = __builtin_amdgcn_mfma_f32_32x32x16_bf16(
          frag_from(w.x, w.y, w.z, w.w),
          frag_from(hb[ks][0], hb[ks][1], hb[ks][2], hb[ks][3]), a2, 0, 0, 0);
    }
    unsigned pk[8];
#pragma unroll
    for (int rq = 0; rq < 4; ++rq) {
      const int o0 = 32*mf2 + 8*rq + 4*h;
      float4 b2c = *(const float4*)(b2 + o0);
      float4 atc = *(const float4*)(attn + o0);
      float m0 = (a2[rq*4+0] + b2c.x) * xq[rq].x;
      float m1 = (a2[rq*4+1] + b2c.y) * xq[rq].y;
      float m2 = (a2[rq*4+2] + b2c.z) * xq[rq].z;
      float m3 = (a2[rq*4+3] + b2c.w) * xq[rq].w;
      score = fmaf(m0, atc.x, score);
      score = fmaf(m1, atc.y, score);
      score = fmaf(m2, atc.z, score);
      score = fmaf(m3, atc.w, score);
      pk[2*rq]   = cvtpk(m0, m1);
      pk[2*rq+1] = cvtpk(m2, m3);
    }
    if (e < E) {
      ux4* dst = (ux4*)(msgp + (long long)pos * 64 + 16*mf2 + 8*h);
      ux4 s0, s1;
      s0.x = pk[0]; s0.y = pk[1]; s0.z = pk[2]; s0.w = pk[3];
      s1.x = pk[4]; s1.y = pk[5]; s1.z = pk[6]; s1.w = pk[7];
      __builtin_nontemporal_store(s0, dst);
      __builtin_nontemporal_store(s1, dst + 1);
    }
  }
  score += __shfl_xor(score, 32);
  if (h == 0 && e < E) {
    scoreS[pos] = score;
    scorig[e]   = score;   // overwrites pose[e] (already consumed by this wave)
  }
}

// ---------------- gather: per-node softmax + weighted sum (sequential streams) ----------------
__global__ __launch_bounds__(256)
void k_gather(const unsigned* __restrict__ msgp, const float* __restrict__ scoreS,
              const int* __restrict__ rowptr, float* __restrict__ lse,
              float* __restrict__ out, int N)
{
  const int lane = threadIdx.x & 63;
  const int node = blockIdx.x * 4 + (threadIdx.x >> 6);
  if (node >= N) return;
  const int end   = rowptr[node];
  const int start = node ? rowptr[node - 1] : 0;
  const int L     = end - start;

  float m = -3.4e38f, s = 0.f;
  for (int c0 = 0; c0 < L; c0 += 64) {
    const int j = c0 + lane;
    float sc = (j < L) ? scoreS[start + j] : -3.4e38f;
    float cm = sc;
#pragma unroll
    for (int off = 32; off; off >>= 1) cm = fmaxf(cm, __shfl_xor(cm, off));
    const float mn = fmaxf(m, cm);
    float ex = (j < L) ? __expf(sc - mn) : 0.f;
#pragma unroll
    for (int off = 32; off; off >>= 1) ex += __shfl_xor(ex, off);
    s = s * __expf(m - mn) + ex;
    m = mn;
  }
  const float lsev = m + logf(s + 1e-16f);
  if (lane == 0) lse[node] = lsev;

  float2 acc; acc.x = 0.f; acc.y = 0.f;
  for (int c0 = 0; c0 < L; c0 += 64) {
    const int j = c0 + lane;
    float w = (j < L) ? __expf(scoreS[start + j] - lsev) : 0.f;
    const int jn = min(64, L - c0);
#pragma unroll 4
    for (int j2 = 0; j2 < jn; ++j2) {
      float wj = __shfl(w, j2);
      unsigned md = __builtin_nontemporal_load(
          msgp + (long long)(start + c0 + j2) * 64 + lane);
      acc.x = fmaf(wj, __uint_as_float(md << 16),          acc.x);
      acc.y = fmaf(wj, __uint_as_float(md & 0xffff0000u), acc.y);
    }
  }
  const int mf2 = lane >> 4, hh = (lane >> 3) & 1, rq = (lane >> 1) & 3, half = lane & 1;
  const int ch0 = 32*mf2 + 8*rq + 4*hh + 2*half;
  *(float2*)(out + (long long)node * 128 + ch0) = acc;
}

// ---------------- final attention weights (original edge order, in-place) ----------------
__global__ void k_wfin(float* __restrict__ wbuf, const int* __restrict__ ei,
                       const float* __restrict__ lse, int E){
  for (long long i = (long long)blockIdx.x * 256 + threadIdx.x; i < E;
       i += (long long)gridDim.x * 256) {
    float scv = wbuf[i];
    int tg = ei[E + i];
    wbuf[i] = __expf(scv - lse[tg]);
  }
}

extern "C" void kernel_launch(void* const* d_in, const int* in_sizes, int n_in,
                              void* d_out, int out_size, void* d_ws, size_t ws_size,
                              hipStream_t stream)
{
  const float* x    = (const float*)d_in[0];
  const int*   ei   = (const int*)d_in[1];
  const float* ea   = (const float*)d_in[2];
  const float* W1   = (const float*)d_in[3];
  const float* b1   = (const float*)d_in[4];
  const float* W2   = (const float*)d_in[5];
  const float* b2   = (const float*)d_in[6];
  const float* attn = (const float*)d_in[7];
  const int N = in_sizes[0] / 128;
  const int E = in_sizes[2] / 64;
  if (E <= 0 || N <= 0) return;

  float* out   = (float*)d_out;
  float* wregN = out + (long long)N * 128;   // E-float region: pose -> scores -> weights
  ux4*   Wf    = (ux4*)d_out;                // node region start: W fragments (overwritten by gather)

  char* wsb = (char*)d_ws;
  unsigned* msgp   = (unsigned*)wsb;                                  // E*256 B
  float*    scoreS = (float*)(wsb + (size_t)E * 256);                 // E*4
  int*      rowptr = (int*)(wsb + (size_t)E * 256 + (size_t)E * 4);   // N*4
  float*    lse    = (float*)(wsb + (size_t)E * 260 + (size_t)N * 4); // N*4
  const size_t need = (size_t)E * 260 + (size_t)N * 8;
  if (ws_size < need) return;

  (void)hipMemsetAsync(rowptr, 0, (size_t)N * 4, stream);
  k_prep<<<12, 256, 0, stream>>>(W1, W2, Wf);
  k_hist<<<1024, 256, 0, stream>>>(ei, rowptr, E);
  k_scan<<<1, 1024, 0, stream>>>(rowptr, N);
  k_fill<<<1024, 256, 0, stream>>>(ei, rowptr, (int*)wregN, E);
  k1_fused<<<(E + 127) / 128, 256, 0, stream>>>(x, ei, ea, Wf, b1, b2, attn,
                                                (const int*)wregN, msgp, scoreS,
                                                wregN, E);
  k_gather<<<(N + 3) / 4, 256, 0, stream>>>(msgp, scoreS, rowptr, lse, out, N);
  k_wfin<<<1024, 256, 0, stream>>>(wregN, ei, lse, E);
}

// Round 6
// 344.388 us; speedup vs baseline: 1.2941x; 1.2941x over previous
//
#include <hip/hip_runtime.h>
#include <stdint.h>

typedef short short8 __attribute__((ext_vector_type(8)));
typedef float f32x16 __attribute__((ext_vector_type(16)));
typedef float fx4 __attribute__((ext_vector_type(4)));
typedef unsigned ux4 __attribute__((ext_vector_type(4)));

__device__ __forceinline__ unsigned cvtpk(float lo, float hi){
  unsigned r;
  asm("v_cvt_pk_bf16_f32 %0, %1, %2" : "=v"(r) : "v"(lo), "v"(hi));
  return r;
}

__device__ __forceinline__ short8 frag_from(unsigned a, unsigned b, unsigned c, unsigned d){
  union { unsigned u[4]; short8 s; } t;
  t.u[0] = a; t.u[1] = b; t.u[2] = c; t.u[3] = d;
  return t.s;
}

// ---------------- prep: pack W1^T / W2^T into MFMA A-fragment order ----------------
__global__ void k_prep(const float* __restrict__ W1, const float* __restrict__ W2,
                       ux4* __restrict__ Wf)
{
  const int t = blockIdx.x * 256 + threadIdx.x;
  if (t >= 48 * 64) return;
  const int f = t >> 6, l = t & 63;
  const int r = l & 31, hh = l >> 5;
  float v[8];
  if (f < 16) {
    const int mf = f >> 2, ks = f & 3;
    const int c = 32 * mf + r, kb = ks * 16 + hh * 8;
#pragma unroll
    for (int j = 0; j < 8; ++j) v[j] = W1[(kb + j) * 128 + c];
  } else {
    const int f2 = f - 16, mf2 = f2 >> 3, ks = f2 & 7;
    const int o = 32 * mf2 + r, cb = ks * 16 + hh * 8;
#pragma unroll
    for (int j = 0; j < 8; ++j) v[j] = W2[(cb + j) * 128 + o];
  }
  ux4 d;
  d.x = cvtpk(v[0], v[1]); d.y = cvtpk(v[2], v[3]);
  d.z = cvtpk(v[4], v[5]); d.w = cvtpk(v[6], v[7]);
  Wf[(long long)f * 64 + l] = d;
}

// ---------------- CSR build ----------------
__global__ void k_hist(const int* __restrict__ ei, int* __restrict__ rowptr, int E){
  for (long long i = (long long)blockIdx.x * 256 + threadIdx.x; i < E;
       i += (long long)gridDim.x * 256)
    atomicAdd(&rowptr[ei[E + i]], 1);
}

__global__ __launch_bounds__(1024)
void k_scan(int* __restrict__ p, int N){
  __shared__ int ls[1024];
  const int t = threadIdx.x;
  const int chunk = (N + 1023) >> 10;
  const int c0 = t * chunk, c1 = min(N, c0 + chunk);
  int s = 0;
  for (int i = c0; i < c1; ++i) s += p[i];
  ls[t] = s;
  __syncthreads();
  for (int off = 1; off < 1024; off <<= 1) {
    int add = (t >= off) ? ls[t - off] : 0;
    __syncthreads();
    ls[t] += add;
    __syncthreads();
  }
  int run = (t == 0) ? 0 : ls[t - 1];
  for (int i = c0; i < c1; ++i) { int v = p[i]; p[i] = run; run += v; }
}

__global__ void k_fill(const int* __restrict__ ei, int* __restrict__ rowptr,
                       int* __restrict__ pose, int E){
  for (long long i = (long long)blockIdx.x * 256 + threadIdx.x; i < E;
       i += (long long)gridDim.x * 256) {
    int tg = ei[E + i];
    pose[i] = atomicAdd(&rowptr[tg], 1);
  }
}

// ---------------- K1: fused normalize + MLP (MFMA) + messages + scores ----------------
template<bool FULL>
__global__ __launch_bounds__(256)
void k1_fused(const float* __restrict__ x, const int* __restrict__ ei,
              const float* __restrict__ ea, const ux4* __restrict__ Wf,
              const float* __restrict__ b1, const float* __restrict__ b2,
              const float* __restrict__ attn, const int* __restrict__ pose,
              unsigned* __restrict__ msgp, float* __restrict__ scoreS,
              float* __restrict__ scorig, int E)
{
  const int lane = threadIdx.x & 63;
  const int wv   = threadIdx.x >> 6;
  const int h    = lane >> 5;
  const int r31  = lane & 31;
  const long long e   = (long long)blockIdx.x * 128 + wv * 32 + r31;
  const long long eld = FULL ? e : ((e < E) ? e : (long long)(E - 1));

  const int pos = pose[eld];
  const int src = ei[eld];
  const float* xrow = x + (long long)src * 128;

  // ---- load edge_attr (streamed), convert to bf16 UNNORMALIZED,
  //      accumulate sum of squares; normalization folded into acc1 scale.
  const fx4* earow = (const fx4*)(ea + eld * 64 + h * 8);
  float ss = 0.f;
  unsigned eb[4][4];
#pragma unroll
  for (int ks = 0; ks < 4; ++ks) {
    fx4 p0 = __builtin_nontemporal_load(earow + ks * 4);
    fx4 p1 = __builtin_nontemporal_load(earow + ks * 4 + 1);
    ss = fmaf(p0.x, p0.x, ss); ss = fmaf(p0.y, p0.y, ss);
    ss = fmaf(p0.z, p0.z, ss); ss = fmaf(p0.w, p0.w, ss);
    ss = fmaf(p1.x, p1.x, ss); ss = fmaf(p1.y, p1.y, ss);
    ss = fmaf(p1.z, p1.z, ss); ss = fmaf(p1.w, p1.w, ss);
    eb[ks][0] = cvtpk(p0.x, p0.y); eb[ks][1] = cvtpk(p0.z, p0.w);
    eb[ks][2] = cvtpk(p1.x, p1.y); eb[ks][3] = cvtpk(p1.z, p1.w);
  }
  ss += __shfl_xor(ss, 32);
  const float rin = 1.0f / (sqrtf(ss) + 1e-8f);   // per-edge = per-lane-column scale

  // ---- L1 (staged per mf): h = tanh((ean_un @ W1)*rin + b1), B-fragments in-register ----
  unsigned hb[8][4];
#pragma unroll
  for (int mf = 0; mf < 4; ++mf) {
    f32x16 a1;
#pragma unroll
    for (int i = 0; i < 16; ++i) a1[i] = 0.f;
#pragma unroll
    for (int ks = 0; ks < 4; ++ks) {
      ux4 w = Wf[(mf * 4 + ks) * 64 + lane];
      a1 = __builtin_amdgcn_mfma_f32_32x32x16_bf16(
          frag_from(w.x, w.y, w.z, w.w),
          frag_from(eb[ks][0], eb[ks][1], eb[ks][2], eb[ks][3]), a1, 0, 0, 0);
    }
    float hv[16];
#pragma unroll
    for (int rq = 0; rq < 4; ++rq) {
      float4 bc = *(const float4*)(b1 + 32*mf + 8*rq + 4*h);
#pragma unroll
      for (int i = 0; i < 4; ++i) {
        float pre = fmaf(a1[rq*4+i], rin, ((const float*)&bc)[i]);
        float e2  = __expf(2.0f * pre);
        hv[rq*4+i] = 1.0f - 2.0f / (e2 + 1.0f);
      }
    }
#pragma unroll
    for (int q = 0; q < 2; ++q) {
      unsigned A = cvtpk(hv[q*8+0], hv[q*8+1]);
      unsigned B = cvtpk(hv[q*8+2], hv[q*8+3]);
      unsigned C = cvtpk(hv[q*8+4], hv[q*8+5]);
      unsigned D = cvtpk(hv[q*8+6], hv[q*8+7]);
      unsigned Axr = (unsigned)__shfl_xor((int)A, 32);
      unsigned Bxr = (unsigned)__shfl_xor((int)B, 32);
      unsigned Cxr = (unsigned)__shfl_xor((int)C, 32);
      unsigned Dxr = (unsigned)__shfl_xor((int)D, 32);
      hb[2*mf+q][0] = h ? Cxr : A;
      hb[2*mf+q][1] = h ? Dxr : B;
      hb[2*mf+q][2] = h ? C   : Axr;
      hb[2*mf+q][3] = h ? D   : Bxr;
    }
  }

  // ---- L2 (staged per mf2) + epilogue; x chunk loaded per-mf2 at use ----
  float score = 0.f;
#pragma unroll
  for (int mf2 = 0; mf2 < 4; ++mf2) {
    float4 xq[4];
#pragma unroll
    for (int rq = 0; rq < 4; ++rq)
      xq[rq] = *(const float4*)(xrow + 32*mf2 + 8*rq + 4*h);

    f32x16 a2;
#pragma unroll
    for (int i = 0; i < 16; ++i) a2[i] = 0.f;
#pragma unroll
    for (int ks = 0; ks < 8; ++ks) {
      ux4 w = Wf[(16 + mf2 * 8 + ks) * 64 + lane];
      a2 = __builtin_amdgcn_mfma_f32_32x32x16_bf16(
          frag_from(w.x, w.y, w.z, w.w),
          frag_from(hb[ks][0], hb[ks][1], hb[ks][2], hb[ks][3]), a2, 0, 0, 0);
    }
    unsigned pk[8];
#pragma unroll
    for (int rq = 0; rq < 4; ++rq) {
      const int o0 = 32*mf2 + 8*rq + 4*h;
      float4 b2c = *(const float4*)(b2 + o0);
      float4 atc = *(const float4*)(attn + o0);
      float m0 = (a2[rq*4+0] + b2c.x) * xq[rq].x;
      float m1 = (a2[rq*4+1] + b2c.y) * xq[rq].y;
      float m2 = (a2[rq*4+2] + b2c.z) * xq[rq].z;
      float m3 = (a2[rq*4+3] + b2c.w) * xq[rq].w;
      score = fmaf(m0, atc.x, score);
      score = fmaf(m1, atc.y, score);
      score = fmaf(m2, atc.z, score);
      score = fmaf(m3, atc.w, score);
      pk[2*rq]   = cvtpk(m0, m1);
      pk[2*rq+1] = cvtpk(m2, m3);
    }
    if (FULL || e < E) {
      ux4* dst = (ux4*)(msgp + (long long)pos * 64 + 16*mf2 + 8*h);
      ux4 s0, s1;
      s0.x = pk[0]; s0.y = pk[1]; s0.z = pk[2]; s0.w = pk[3];
      s1.x = pk[4]; s1.y = pk[5]; s1.z = pk[6]; s1.w = pk[7];
      __builtin_nontemporal_store(s0, dst);
      __builtin_nontemporal_store(s1, dst + 1);
    }
  }
  score += __shfl_xor(score, 32);
  if (h == 0 && (FULL || e < E)) {
    scoreS[pos] = score;
    scorig[e]   = score;   // overwrites pose[e] (already consumed by this wave)
  }
}

// ---------------- gather: per-node softmax + weighted sum (sequential streams) ----------------
__global__ __launch_bounds__(256)
void k_gather(const unsigned* __restrict__ msgp, const float* __restrict__ scoreS,
              const int* __restrict__ rowptr, float* __restrict__ lse,
              float* __restrict__ out, int N)
{
  const int lane = threadIdx.x & 63;
  const int node = blockIdx.x * 4 + (threadIdx.x >> 6);
  if (node >= N) return;
  const int end   = rowptr[node];
  const int start = node ? rowptr[node - 1] : 0;
  const int L     = end - start;

  float m = -3.4e38f, s = 0.f;
  for (int c0 = 0; c0 < L; c0 += 64) {
    const int j = c0 + lane;
    float sc = (j < L) ? scoreS[start + j] : -3.4e38f;
    float cm = sc;
#pragma unroll
    for (int off = 32; off; off >>= 1) cm = fmaxf(cm, __shfl_xor(cm, off));
    const float mn = fmaxf(m, cm);
    float ex = (j < L) ? __expf(sc - mn) : 0.f;
#pragma unroll
    for (int off = 32; off; off >>= 1) ex += __shfl_xor(ex, off);
    s = s * __expf(m - mn) + ex;
    m = mn;
  }
  const float lsev = m + logf(s + 1e-16f);
  if (lane == 0) lse[node] = lsev;

  float2 acc; acc.x = 0.f; acc.y = 0.f;
  for (int c0 = 0; c0 < L; c0 += 64) {
    const int j = c0 + lane;
    float w = (j < L) ? __expf(scoreS[start + j] - lsev) : 0.f;
    const int jn = min(64, L - c0);
#pragma unroll 4
    for (int j2 = 0; j2 < jn; ++j2) {
      float wj = __shfl(w, j2);
      unsigned md = __builtin_nontemporal_load(
          msgp + (long long)(start + c0 + j2) * 64 + lane);
      acc.x = fmaf(wj, __uint_as_float(md << 16),          acc.x);
      acc.y = fmaf(wj, __uint_as_float(md & 0xffff0000u), acc.y);
    }
  }
  const int mf2 = lane >> 4, hh = (lane >> 3) & 1, rq = (lane >> 1) & 3, half = lane & 1;
  const int ch0 = 32*mf2 + 8*rq + 4*hh + 2*half;
  *(float2*)(out + (long long)node * 128 + ch0) = acc;
}

// ---------------- final attention weights (original edge order, in-place) ----------------
__global__ void k_wfin(float* __restrict__ wbuf, const int* __restrict__ ei,
                       const float* __restrict__ lse, int E){
  for (long long i = (long long)blockIdx.x * 256 + threadIdx.x; i < E;
       i += (long long)gridDim.x * 256) {
    float scv = wbuf[i];
    int tg = ei[E + i];
    wbuf[i] = __expf(scv - lse[tg]);
  }
}

extern "C" void kernel_launch(void* const* d_in, const int* in_sizes, int n_in,
                              void* d_out, int out_size, void* d_ws, size_t ws_size,
                              hipStream_t stream)
{
  const float* x    = (const float*)d_in[0];
  const int*   ei   = (const int*)d_in[1];
  const float* ea   = (const float*)d_in[2];
  const float* W1   = (const float*)d_in[3];
  const float* b1   = (const float*)d_in[4];
  const float* W2   = (const float*)d_in[5];
  const float* b2   = (const float*)d_in[6];
  const float* attn = (const float*)d_in[7];
  const int N = in_sizes[0] / 128;
  const int E = in_sizes[2] / 64;
  if (E <= 0 || N <= 0) return;

  float* out   = (float*)d_out;
  float* wregN = out + (long long)N * 128;   // E-float region: pose -> scores -> weights
  ux4*   Wf    = (ux4*)d_out;                // node region start: W fragments (overwritten by gather)

  char* wsb = (char*)d_ws;
  unsigned* msgp   = (unsigned*)wsb;                                  // E*256 B
  float*    scoreS = (float*)(wsb + (size_t)E * 256);                 // E*4
  int*      rowptr = (int*)(wsb + (size_t)E * 256 + (size_t)E * 4);   // N*4
  float*    lse    = (float*)(wsb + (size_t)E * 260 + (size_t)N * 4); // N*4
  const size_t need = (size_t)E * 260 + (size_t)N * 8;
  if (ws_size < need) return;

  (void)hipMemsetAsync(rowptr, 0, (size_t)N * 4, stream);
  k_prep<<<12, 256, 0, stream>>>(W1, W2, Wf);
  k_hist<<<1024, 256, 0, stream>>>(ei, rowptr, E);
  k_scan<<<1, 1024, 0, stream>>>(rowptr, N);
  k_fill<<<1024, 256, 0, stream>>>(ei, rowptr, (int*)wregN, E);
  if ((E & 127) == 0)
    k1_fused<true><<<E / 128, 256, 0, stream>>>(x, ei, ea, Wf, b1, b2, attn,
                                                (const int*)wregN, msgp, scoreS,
                                                wregN, E);
  else
    k1_fused<false><<<(E + 127) / 128, 256, 0, stream>>>(x, ei, ea, Wf, b1, b2, attn,
                                                         (const int*)wregN, msgp, scoreS,
                                                         wregN, E);
  k_gather<<<(N + 3) / 4, 256, 0, stream>>>(msgp, scoreS, rowptr, lse, out, N);
  k_wfin<<<1024, 256, 0, stream>>>(wregN, ei, lse, E);
}

// Round 7
// 344.137 us; speedup vs baseline: 1.2950x; 1.0007x over previous
//
#include <hip/hip_runtime.h>
#include <stdint.h>

typedef short short8 __attribute__((ext_vector_type(8)));
typedef float f32x16 __attribute__((ext_vector_type(16)));
typedef float fx4 __attribute__((ext_vector_type(4)));
typedef unsigned ux4 __attribute__((ext_vector_type(4)));

__device__ __forceinline__ unsigned cvtpk(float lo, float hi){
  unsigned r;
  asm("v_cvt_pk_bf16_f32 %0, %1, %2" : "=v"(r) : "v"(lo), "v"(hi));
  return r;
}

__device__ __forceinline__ short8 frag_from(unsigned a, unsigned b, unsigned c, unsigned d){
  union { unsigned u[4]; short8 s; } t;
  t.u[0] = a; t.u[1] = b; t.u[2] = c; t.u[3] = d;
  return t.s;
}

// ---------------- prep: pack W1^T / W2^T into MFMA A-fragment order ----------------
__global__ void k_prep(const float* __restrict__ W1, const float* __restrict__ W2,
                       ux4* __restrict__ Wf)
{
  const int t = blockIdx.x * 256 + threadIdx.x;
  if (t >= 48 * 64) return;
  const int f = t >> 6, l = t & 63;
  const int r = l & 31, hh = l >> 5;
  float v[8];
  if (f < 16) {
    const int mf = f >> 2, ks = f & 3;
    const int c = 32 * mf + r, kb = ks * 16 + hh * 8;
#pragma unroll
    for (int j = 0; j < 8; ++j) v[j] = W1[(kb + j) * 128 + c];
  } else {
    const int f2 = f - 16, mf2 = f2 >> 3, ks = f2 & 7;
    const int o = 32 * mf2 + r, cb = ks * 16 + hh * 8;
#pragma unroll
    for (int j = 0; j < 8; ++j) v[j] = W2[(cb + j) * 128 + o];
  }
  ux4 d;
  d.x = cvtpk(v[0], v[1]); d.y = cvtpk(v[2], v[3]);
  d.z = cvtpk(v[4], v[5]); d.w = cvtpk(v[6], v[7]);
  Wf[(long long)f * 64 + l] = d;
}

// ---------------- CSR build ----------------
__global__ void k_hist(const int* __restrict__ ei, int* __restrict__ rowptr, int E){
  for (long long i = (long long)blockIdx.x * 256 + threadIdx.x; i < E;
       i += (long long)gridDim.x * 256)
    atomicAdd(&rowptr[ei[E + i]], 1);
}

__global__ __launch_bounds__(1024)
void k_scan(int* __restrict__ p, int N){
  __shared__ int ls[1024];
  const int t = threadIdx.x;
  const int chunk = (N + 1023) >> 10;
  const int c0 = t * chunk, c1 = min(N, c0 + chunk);
  int s = 0;
  for (int i = c0; i < c1; ++i) s += p[i];
  ls[t] = s;
  __syncthreads();
  for (int off = 1; off < 1024; off <<= 1) {
    int add = (t >= off) ? ls[t - off] : 0;
    __syncthreads();
    ls[t] += add;
    __syncthreads();
  }
  int run = (t == 0) ? 0 : ls[t - 1];
  for (int i = c0; i < c1; ++i) { int v = p[i]; p[i] = run; run += v; }
}

__global__ void k_fill(const int* __restrict__ ei, int* __restrict__ rowptr,
                       int* __restrict__ pose, int E){
  for (long long i = (long long)blockIdx.x * 256 + threadIdx.x; i < E;
       i += (long long)gridDim.x * 256) {
    int tg = ei[E + i];
    pose[i] = atomicAdd(&rowptr[tg], 1);
  }
}

// ---------------- K1: fused normalize + MLP (MFMA) + messages + scores ----------------
template<bool FULL>
__global__ __launch_bounds__(256, 4)
void k1_fused(const float* __restrict__ x, const int* __restrict__ ei,
              const float* __restrict__ ea, const ux4* __restrict__ Wf,
              const float* __restrict__ b1, const float* __restrict__ b2,
              const float* __restrict__ attn, const int* __restrict__ pose,
              unsigned* __restrict__ msgp, float* __restrict__ scoreS,
              float* __restrict__ scorig, int E)
{
  const int lane = threadIdx.x & 63;
  const int wv   = threadIdx.x >> 6;
  const int h    = lane >> 5;
  const int r31  = lane & 31;
  const long long e   = (long long)blockIdx.x * 128 + wv * 32 + r31;
  const long long eld = FULL ? e : ((e < E) ? e : (long long)(E - 1));

  const int pos = pose[eld];
  const int src = ei[eld];
  const float* xrow = x + (long long)src * 128;

  // ---- load edge_attr (streamed), convert to bf16 UNNORMALIZED,
  //      accumulate sum of squares; normalization folded into acc1 scale.
  const fx4* earow = (const fx4*)(ea + eld * 64 + h * 8);
  float ss = 0.f;
  unsigned eb[4][4];
#pragma unroll
  for (int ks = 0; ks < 4; ++ks) {
    fx4 p0 = __builtin_nontemporal_load(earow + ks * 4);
    fx4 p1 = __builtin_nontemporal_load(earow + ks * 4 + 1);
    ss = fmaf(p0.x, p0.x, ss); ss = fmaf(p0.y, p0.y, ss);
    ss = fmaf(p0.z, p0.z, ss); ss = fmaf(p0.w, p0.w, ss);
    ss = fmaf(p1.x, p1.x, ss); ss = fmaf(p1.y, p1.y, ss);
    ss = fmaf(p1.z, p1.z, ss); ss = fmaf(p1.w, p1.w, ss);
    eb[ks][0] = cvtpk(p0.x, p0.y); eb[ks][1] = cvtpk(p0.z, p0.w);
    eb[ks][2] = cvtpk(p1.x, p1.y); eb[ks][3] = cvtpk(p1.z, p1.w);
  }
  ss += __shfl_xor(ss, 32);
  const float rin = 1.0f / (sqrtf(ss) + 1e-8f);   // per-edge = per-lane-column scale

  // ---- L1 (staged per mf): h = tanh((ean_un @ W1)*rin + b1), B-fragments in-register ----
  unsigned hb[8][4];
#pragma unroll
  for (int mf = 0; mf < 4; ++mf) {
    f32x16 a1;
#pragma unroll
    for (int i = 0; i < 16; ++i) a1[i] = 0.f;
#pragma unroll
    for (int ks = 0; ks < 4; ++ks) {
      ux4 w = Wf[(mf * 4 + ks) * 64 + lane];
      a1 = __builtin_amdgcn_mfma_f32_32x32x16_bf16(
          frag_from(w.x, w.y, w.z, w.w),
          frag_from(eb[ks][0], eb[ks][1], eb[ks][2], eb[ks][3]), a1, 0, 0, 0);
    }
    float hv[16];
#pragma unroll
    for (int rq = 0; rq < 4; ++rq) {
      float4 bc = *(const float4*)(b1 + 32*mf + 8*rq + 4*h);
#pragma unroll
      for (int i = 0; i < 4; ++i) {
        float pre = fmaf(a1[rq*4+i], rin, ((const float*)&bc)[i]);
        float e2  = __expf(2.0f * pre);
        hv[rq*4+i] = 1.0f - 2.0f / (e2 + 1.0f);
      }
    }
#pragma unroll
    for (int q = 0; q < 2; ++q) {
      unsigned A = cvtpk(hv[q*8+0], hv[q*8+1]);
      unsigned B = cvtpk(hv[q*8+2], hv[q*8+3]);
      unsigned C = cvtpk(hv[q*8+4], hv[q*8+5]);
      unsigned D = cvtpk(hv[q*8+6], hv[q*8+7]);
      unsigned Axr = (unsigned)__shfl_xor((int)A, 32);
      unsigned Bxr = (unsigned)__shfl_xor((int)B, 32);
      unsigned Cxr = (unsigned)__shfl_xor((int)C, 32);
      unsigned Dxr = (unsigned)__shfl_xor((int)D, 32);
      hb[2*mf+q][0] = h ? Cxr : A;
      hb[2*mf+q][1] = h ? Dxr : B;
      hb[2*mf+q][2] = h ? C   : Axr;
      hb[2*mf+q][3] = h ? D   : Bxr;
    }
  }

  // ---- L2 (staged per mf2) + epilogue; x chunk loaded per-mf2 at use ----
  float score = 0.f;
#pragma unroll
  for (int mf2 = 0; mf2 < 4; ++mf2) {
    float4 xq[4];
#pragma unroll
    for (int rq = 0; rq < 4; ++rq)
      xq[rq] = *(const float4*)(xrow + 32*mf2 + 8*rq + 4*h);

    f32x16 a2;
#pragma unroll
    for (int i = 0; i < 16; ++i) a2[i] = 0.f;
#pragma unroll
    for (int ks = 0; ks < 8; ++ks) {
      ux4 w = Wf[(16 + mf2 * 8 + ks) * 64 + lane];
      a2 = __builtin_amdgcn_mfma_f32_32x32x16_bf16(
          frag_from(w.x, w.y, w.z, w.w),
          frag_from(hb[ks][0], hb[ks][1], hb[ks][2], hb[ks][3]), a2, 0, 0, 0);
    }
    unsigned pk[8];
#pragma unroll
    for (int rq = 0; rq < 4; ++rq) {
      const int o0 = 32*mf2 + 8*rq + 4*h;
      float4 b2c = *(const float4*)(b2 + o0);
      float4 atc = *(const float4*)(attn + o0);
      float m0 = (a2[rq*4+0] + b2c.x) * xq[rq].x;
      float m1 = (a2[rq*4+1] + b2c.y) * xq[rq].y;
      float m2 = (a2[rq*4+2] + b2c.z) * xq[rq].z;
      float m3 = (a2[rq*4+3] + b2c.w) * xq[rq].w;
      score = fmaf(m0, atc.x, score);
      score = fmaf(m1, atc.y, score);
      score = fmaf(m2, atc.z, score);
      score = fmaf(m3, atc.w, score);
      pk[2*rq]   = cvtpk(m0, m1);
      pk[2*rq+1] = cvtpk(m2, m3);
    }
    if (FULL || e < E) {
      ux4* dst = (ux4*)(msgp + (long long)pos * 64 + 16*mf2 + 8*h);
      ux4 s0, s1;
      s0.x = pk[0]; s0.y = pk[1]; s0.z = pk[2]; s0.w = pk[3];
      s1.x = pk[4]; s1.y = pk[5]; s1.z = pk[6]; s1.w = pk[7];
      __builtin_nontemporal_store(s0, dst);
      __builtin_nontemporal_store(s1, dst + 1);
    }
  }
  score += __shfl_xor(score, 32);
  if (h == 0 && (FULL || e < E)) {
    scoreS[pos] = score;
    scorig[e]   = score;   // overwrites pose[e] (already consumed by this wave)
  }
}

// ---------------- gather: per-node softmax + weighted sum (sequential streams) ----------------
__global__ __launch_bounds__(256)
void k_gather(const unsigned* __restrict__ msgp, const float* __restrict__ scoreS,
              const int* __restrict__ rowptr, float* __restrict__ lse,
              float* __restrict__ out, int N)
{
  const int lane = threadIdx.x & 63;
  const int node = blockIdx.x * 4 + (threadIdx.x >> 6);
  if (node >= N) return;
  const int end   = rowptr[node];
  const int start = node ? rowptr[node - 1] : 0;
  const int L     = end - start;

  float m = -3.4e38f, s = 0.f;
  for (int c0 = 0; c0 < L; c0 += 64) {
    const int j = c0 + lane;
    float sc = (j < L) ? scoreS[start + j] : -3.4e38f;
    float cm = sc;
#pragma unroll
    for (int off = 32; off; off >>= 1) cm = fmaxf(cm, __shfl_xor(cm, off));
    const float mn = fmaxf(m, cm);
    float ex = (j < L) ? __expf(sc - mn) : 0.f;
#pragma unroll
    for (int off = 32; off; off >>= 1) ex += __shfl_xor(ex, off);
    s = s * __expf(m - mn) + ex;
    m = mn;
  }
  const float lsev = m + logf(s + 1e-16f);
  if (lane == 0) lse[node] = lsev;

  float2 acc; acc.x = 0.f; acc.y = 0.f;
  for (int c0 = 0; c0 < L; c0 += 64) {
    const int j = c0 + lane;
    float w = (j < L) ? __expf(scoreS[start + j] - lsev) : 0.f;
    const int jn = min(64, L - c0);
#pragma unroll 4
    for (int j2 = 0; j2 < jn; ++j2) {
      float wj = __shfl(w, j2);
      unsigned md = __builtin_nontemporal_load(
          msgp + (long long)(start + c0 + j2) * 64 + lane);
      acc.x = fmaf(wj, __uint_as_float(md << 16),          acc.x);
      acc.y = fmaf(wj, __uint_as_float(md & 0xffff0000u), acc.y);
    }
  }
  const int mf2 = lane >> 4, hh = (lane >> 3) & 1, rq = (lane >> 1) & 3, half = lane & 1;
  const int ch0 = 32*mf2 + 8*rq + 4*hh + 2*half;
  *(float2*)(out + (long long)node * 128 + ch0) = acc;
}

// ---------------- final attention weights (original edge order, in-place) ----------------
__global__ void k_wfin(float* __restrict__ wbuf, const int* __restrict__ ei,
                       const float* __restrict__ lse, int E){
  for (long long i = (long long)blockIdx.x * 256 + threadIdx.x; i < E;
       i += (long long)gridDim.x * 256) {
    float scv = wbuf[i];
    int tg = ei[E + i];
    wbuf[i] = __expf(scv - lse[tg]);
  }
}

extern "C" void kernel_launch(void* const* d_in, const int* in_sizes, int n_in,
                              void* d_out, int out_size, void* d_ws, size_t ws_size,
                              hipStream_t stream)
{
  const float* x    = (const float*)d_in[0];
  const int*   ei   = (const int*)d_in[1];
  const float* ea   = (const float*)d_in[2];
  const float* W1   = (const float*)d_in[3];
  const float* b1   = (const float*)d_in[4];
  const float* W2   = (const float*)d_in[5];
  const float* b2   = (const float*)d_in[6];
  const float* attn = (const float*)d_in[7];
  const int N = in_sizes[0] / 128;
  const int E = in_sizes[2] / 64;
  if (E <= 0 || N <= 0) return;

  float* out   = (float*)d_out;
  float* wregN = out + (long long)N * 128;   // E-float region: pose -> scores -> weights
  ux4*   Wf    = (ux4*)d_out;                // node region start: W fragments (overwritten by gather)

  char* wsb = (char*)d_ws;
  unsigned* msgp   = (unsigned*)wsb;                                  // E*256 B
  float*    scoreS = (float*)(wsb + (size_t)E * 256);                 // E*4
  int*      rowptr = (int*)(wsb + (size_t)E * 256 + (size_t)E * 4);   // N*4
  float*    lse    = (float*)(wsb + (size_t)E * 260 + (size_t)N * 4); // N*4
  const size_t need = (size_t)E * 260 + (size_t)N * 8;
  if (ws_size < need) return;

  (void)hipMemsetAsync(rowptr, 0, (size_t)N * 4, stream);
  k_prep<<<12, 256, 0, stream>>>(W1, W2, Wf);
  k_hist<<<1024, 256, 0, stream>>>(ei, rowptr, E);
  k_scan<<<1, 1024, 0, stream>>>(rowptr, N);
  k_fill<<<1024, 256, 0, stream>>>(ei, rowptr, (int*)wregN, E);
  if ((E & 127) == 0)
    k1_fused<true><<<E / 128, 256, 0, stream>>>(x, ei, ea, Wf, b1, b2, attn,
                                                (const int*)wregN, msgp, scoreS,
                                                wregN, E);
  else
    k1_fused<false><<<(E + 127) / 128, 256, 0, stream>>>(x, ei, ea, Wf, b1, b2, attn,
                                                         (const int*)wregN, msgp, scoreS,
                                                         wregN, E);
  k_gather<<<(N + 3) / 4, 256, 0, stream>>>(msgp, scoreS, rowptr, lse, out, N);
  k_wfin<<<1024, 256, 0, stream>>>(wregN, ei, lse, E);
}

// Round 8
// 295.241 us; speedup vs baseline: 1.5095x; 1.1656x over previous
//
#include <hip/hip_runtime.h>
#include <stdint.h>

typedef short short8 __attribute__((ext_vector_type(8)));
typedef float f32x16 __attribute__((ext_vector_type(16)));
typedef unsigned ux4 __attribute__((ext_vector_type(4)));

__device__ __forceinline__ unsigned cvtpk(float lo, float hi){
  unsigned r;
  asm("v_cvt_pk_bf16_f32 %0, %1, %2" : "=v"(r) : "v"(lo), "v"(hi));
  return r;
}

__device__ __forceinline__ short8 frag_from(unsigned a, unsigned b, unsigned c, unsigned d){
  union { unsigned u[4]; short8 s; } t;
  t.u[0] = a; t.u[1] = b; t.u[2] = c; t.u[3] = d;
  return t.s;
}

// ---------------- prep: pack W1^T / W2^T into MFMA A-fragment order ----------------
__global__ void k_prep(const float* __restrict__ W1, const float* __restrict__ W2,
                       ux4* __restrict__ Wf)
{
  const int t = blockIdx.x * 256 + threadIdx.x;
  if (t >= 48 * 64) return;
  const int f = t >> 6, l = t & 63;
  const int r = l & 31, hh = l >> 5;
  float v[8];
  if (f < 16) {
    const int mf = f >> 2, ks = f & 3;
    const int c = 32 * mf + r, kb = ks * 16 + hh * 8;
#pragma unroll
    for (int j = 0; j < 8; ++j) v[j] = W1[(kb + j) * 128 + c];
  } else {
    const int f2 = f - 16, mf2 = f2 >> 3, ks = f2 & 7;
    const int o = 32 * mf2 + r, cb = ks * 16 + hh * 8;
#pragma unroll
    for (int j = 0; j < 8; ++j) v[j] = W2[(cb + j) * 128 + o];
  }
  ux4 d;
  d.x = cvtpk(v[0], v[1]); d.y = cvtpk(v[2], v[3]);
  d.z = cvtpk(v[4], v[5]); d.w = cvtpk(v[6], v[7]);
  Wf[(long long)f * 64 + l] = d;
}

// ---------------- CSR build ----------------
__global__ void k_hist(const int* __restrict__ ei, int* __restrict__ rowptr, int E){
  for (long long i = (long long)blockIdx.x * 256 + threadIdx.x; i < E;
       i += (long long)gridDim.x * 256)
    atomicAdd(&rowptr[ei[E + i]], 1);
}

__global__ __launch_bounds__(1024)
void k_scan(int* __restrict__ p, int N){
  __shared__ int ls[1024];
  const int t = threadIdx.x;
  const int chunk = (N + 1023) >> 10;
  const int c0 = t * chunk, c1 = min(N, c0 + chunk);
  int s = 0;
  for (int i = c0; i < c1; ++i) s += p[i];
  ls[t] = s;
  __syncthreads();
  for (int off = 1; off < 1024; off <<= 1) {
    int add = (t >= off) ? ls[t - off] : 0;
    __syncthreads();
    ls[t] += add;
    __syncthreads();
  }
  int run = (t == 0) ? 0 : ls[t - 1];
  for (int i = c0; i < c1; ++i) { int v = p[i]; p[i] = run; run += v; }
}

// fill: pose[i] = CSR position of edge i; eidx[pos] = i (inverse permutation)
__global__ void k_fill(const int* __restrict__ ei, int* __restrict__ rowptr,
                       int* __restrict__ pose, int* __restrict__ eidx, int E){
  for (long long i = (long long)blockIdx.x * 256 + threadIdx.x; i < E;
       i += (long long)gridDim.x * 256) {
    int tg = ei[E + i];
    int pos = atomicAdd(&rowptr[tg], 1);
    pose[i] = pos;
    eidx[pos] = (int)i;
  }
}

// ---------------- K1: CSR-ordered fused normalize + MLP (MFMA) + messages + scores ----
// p = CSR position (sequential); e = eidx[p] (original edge). Big writes sequential,
// ea reads scattered 256B rows, ei[e] random 4B from L2-resident table.
__global__ __launch_bounds__(256)
void k1_fused(const float* __restrict__ x, const int* __restrict__ ei,
              const float* __restrict__ ea, const ux4* __restrict__ Wf,
              const float* __restrict__ b1, const float* __restrict__ b2,
              const float* __restrict__ attn, const int* __restrict__ eidx,
              unsigned* __restrict__ msgp, float* __restrict__ scoreS, int E)
{
  const int lane = threadIdx.x & 63;
  const int wv   = threadIdx.x >> 6;
  const int h    = lane >> 5;
  const int r31  = lane & 31;
  const long long p   = (long long)blockIdx.x * 128 + wv * 32 + r31;
  const long long pld = (p < E) ? p : (long long)(E - 1);

  const int e   = eidx[pld];
  const int src = ei[e];
  const float* xrow = x + (long long)src * 128;

  // ---- load edge_attr row (random 256B row, full lines) + normalize ----
  float av[32];
  const float* earow = ea + (long long)e * 64 + h * 8;
#pragma unroll
  for (int ks = 0; ks < 4; ++ks) {
    float4 p0 = *(const float4*)(earow + ks * 16);
    float4 p1 = *(const float4*)(earow + ks * 16 + 4);
    av[ks*8+0] = p0.x; av[ks*8+1] = p0.y; av[ks*8+2] = p0.z; av[ks*8+3] = p0.w;
    av[ks*8+4] = p1.x; av[ks*8+5] = p1.y; av[ks*8+6] = p1.z; av[ks*8+7] = p1.w;
  }
  float ss = 0.f;
#pragma unroll
  for (int i = 0; i < 32; ++i) ss = fmaf(av[i], av[i], ss);
  ss += __shfl_xor(ss, 32);
  const float rin = 1.0f / (sqrtf(ss) + 1e-8f);

  unsigned eb[4][4];
#pragma unroll
  for (int ks = 0; ks < 4; ++ks)
#pragma unroll
    for (int d = 0; d < 4; ++d)
      eb[ks][d] = cvtpk(av[ks*8+2*d] * rin, av[ks*8+2*d+1] * rin);

  // ---- prefetch x row, first half, hidden under L1+tanh ----
  float4 xA[8];
#pragma unroll
  for (int i = 0; i < 8; ++i) {
    const int mf2 = i >> 2, rq = i & 3;
    xA[i] = *(const float4*)(xrow + 32*mf2 + 8*rq + 4*h);
  }
  asm volatile("" ::: "memory");

  // ---- L1 (staged per mf): h = tanh(ean @ W1 + b1), B-fragments in-register ----
  unsigned hb[8][4];
#pragma unroll
  for (int mf = 0; mf < 4; ++mf) {
    f32x16 a1;
#pragma unroll
    for (int i = 0; i < 16; ++i) a1[i] = 0.f;
#pragma unroll
    for (int ks = 0; ks < 4; ++ks) {
      ux4 w = Wf[(mf * 4 + ks) * 64 + lane];
      a1 = __builtin_amdgcn_mfma_f32_32x32x16_bf16(
          frag_from(w.x, w.y, w.z, w.w),
          frag_from(eb[ks][0], eb[ks][1], eb[ks][2], eb[ks][3]), a1, 0, 0, 0);
    }
    float hv[16];
#pragma unroll
    for (int rq = 0; rq < 4; ++rq) {
      float4 bc = *(const float4*)(b1 + 32*mf + 8*rq + 4*h);
#pragma unroll
      for (int i = 0; i < 4; ++i) {
        float pre = a1[rq*4+i] + ((const float*)&bc)[i];
        float e2  = __expf(2.0f * pre);
        hv[rq*4+i] = 1.0f - 2.0f / (e2 + 1.0f);
      }
    }
#pragma unroll
    for (int q = 0; q < 2; ++q) {
      unsigned A = cvtpk(hv[q*8+0], hv[q*8+1]);
      unsigned B = cvtpk(hv[q*8+2], hv[q*8+3]);
      unsigned C = cvtpk(hv[q*8+4], hv[q*8+5]);
      unsigned D = cvtpk(hv[q*8+6], hv[q*8+7]);
      unsigned Axr = (unsigned)__shfl_xor((int)A, 32);
      unsigned Bxr = (unsigned)__shfl_xor((int)B, 32);
      unsigned Cxr = (unsigned)__shfl_xor((int)C, 32);
      unsigned Dxr = (unsigned)__shfl_xor((int)D, 32);
      hb[2*mf+q][0] = h ? Cxr : A;
      hb[2*mf+q][1] = h ? Dxr : B;
      hb[2*mf+q][2] = h ? C   : Axr;
      hb[2*mf+q][3] = h ? D   : Bxr;
    }
  }

  // ---- prefetch x row, second half, hidden under L2 MFMAs ----
  float4 xB[8];
#pragma unroll
  for (int i = 0; i < 8; ++i) {
    const int mf2 = 2 + (i >> 2), rq = i & 3;
    xB[i] = *(const float4*)(xrow + 32*mf2 + 8*rq + 4*h);
  }
  asm volatile("" ::: "memory");

  // ---- L2 (staged per mf2) + epilogue; sequential stores at p ----
  float score = 0.f;
#pragma unroll
  for (int mf2 = 0; mf2 < 4; ++mf2) {
    f32x16 a2;
#pragma unroll
    for (int i = 0; i < 16; ++i) a2[i] = 0.f;
#pragma unroll
    for (int ks = 0; ks < 8; ++ks) {
      ux4 w = Wf[(16 + mf2 * 8 + ks) * 64 + lane];
      a2 = __builtin_amdgcn_mfma_f32_32x32x16_bf16(
          frag_from(w.x, w.y, w.z, w.w),
          frag_from(hb[ks][0], hb[ks][1], hb[ks][2], hb[ks][3]), a2, 0, 0, 0);
    }
    unsigned pk[8];
#pragma unroll
    for (int rq = 0; rq < 4; ++rq) {
      const int o0 = 32*mf2 + 8*rq + 4*h;
      float4 b2c = *(const float4*)(b2 + o0);
      float4 atc = *(const float4*)(attn + o0);
      float4 xc  = (mf2 < 2) ? xA[mf2*4+rq] : xB[(mf2-2)*4+rq];
      float m0 = (a2[rq*4+0] + b2c.x) * xc.x;
      float m1 = (a2[rq*4+1] + b2c.y) * xc.y;
      float m2 = (a2[rq*4+2] + b2c.z) * xc.z;
      float m3 = (a2[rq*4+3] + b2c.w) * xc.w;
      score = fmaf(m0, atc.x, score);
      score = fmaf(m1, atc.y, score);
      score = fmaf(m2, atc.z, score);
      score = fmaf(m3, atc.w, score);
      pk[2*rq]   = cvtpk(m0, m1);
      pk[2*rq+1] = cvtpk(m2, m3);
    }
    if (p < E) {
      ux4* dst = (ux4*)(msgp + p * 64 + 16*mf2 + 8*h);
      ux4 s0, s1;
      s0.x = pk[0]; s0.y = pk[1]; s0.z = pk[2]; s0.w = pk[3];
      s1.x = pk[4]; s1.y = pk[5]; s1.z = pk[6]; s1.w = pk[7];
      dst[0] = s0; dst[1] = s1;
    }
  }
  score += __shfl_xor(score, 32);
  if (h == 0 && p < E) scoreS[p] = score;
}

// ---------------- gather: per-node softmax + weighted sum (sequential streams) ----------------
__global__ __launch_bounds__(256)
void k_gather(const unsigned* __restrict__ msgp, const float* __restrict__ scoreS,
              const int* __restrict__ rowptr, float* __restrict__ lse,
              float* __restrict__ out, int N)
{
  const int lane = threadIdx.x & 63;
  const int node = blockIdx.x * 4 + (threadIdx.x >> 6);
  if (node >= N) return;
  const int end   = rowptr[node];
  const int start = node ? rowptr[node - 1] : 0;
  const int L     = end - start;

  float m = -3.4e38f, s = 0.f;
  for (int c0 = 0; c0 < L; c0 += 64) {
    const int j = c0 + lane;
    float sc = (j < L) ? scoreS[start + j] : -3.4e38f;
    float cm = sc;
#pragma unroll
    for (int off = 32; off; off >>= 1) cm = fmaxf(cm, __shfl_xor(cm, off));
    const float mn = fmaxf(m, cm);
    float ex = (j < L) ? __expf(sc - mn) : 0.f;
#pragma unroll
    for (int off = 32; off; off >>= 1) ex += __shfl_xor(ex, off);
    s = s * __expf(m - mn) + ex;
    m = mn;
  }
  const float lsev = m + logf(s + 1e-16f);
  if (lane == 0) lse[node] = lsev;

  float2 acc; acc.x = 0.f; acc.y = 0.f;
  for (int c0 = 0; c0 < L; c0 += 64) {
    const int j = c0 + lane;
    float w = (j < L) ? __expf(scoreS[start + j] - lsev) : 0.f;
    const int jn = min(64, L - c0);
#pragma unroll 4
    for (int j2 = 0; j2 < jn; ++j2) {
      float wj = __shfl(w, j2);
      unsigned md = msgp[(long long)(start + c0 + j2) * 64 + lane];
      acc.x = fmaf(wj, __uint_as_float(md << 16),          acc.x);
      acc.y = fmaf(wj, __uint_as_float(md & 0xffff0000u), acc.y);
    }
  }
  const int mf2 = lane >> 4, hh = (lane >> 3) & 1, rq = (lane >> 1) & 3, half = lane & 1;
  const int ch0 = 32*mf2 + 8*rq + 4*hh + 2*half;
  *(float2*)(out + (long long)node * 128 + ch0) = acc;
}

// ---------------- final attention weights: w[e] = exp(scoreS[pose[e]] - lse[tg]) ------
// pose buffer is reused in-place for the weight output (all accesses as int).
__global__ void k_wfin(int* __restrict__ pw, const int* __restrict__ ei,
                       const float* __restrict__ scoreS, const float* __restrict__ lse,
                       int E){
  for (long long i = (long long)blockIdx.x * 256 + threadIdx.x; i < E;
       i += (long long)gridDim.x * 256) {
    int pos = pw[i];                        // sequential read (L2-resident table)
    float w = __expf(scoreS[pos] - lse[ei[E + i]]);
    pw[i] = __float_as_int(w);
  }
}

extern "C" void kernel_launch(void* const* d_in, const int* in_sizes, int n_in,
                              void* d_out, int out_size, void* d_ws, size_t ws_size,
                              hipStream_t stream)
{
  const float* x    = (const float*)d_in[0];
  const int*   ei   = (const int*)d_in[1];
  const float* ea   = (const float*)d_in[2];
  const float* W1   = (const float*)d_in[3];
  const float* b1   = (const float*)d_in[4];
  const float* W2   = (const float*)d_in[5];
  const float* b2   = (const float*)d_in[6];
  const float* attn = (const float*)d_in[7];
  const int N = in_sizes[0] / 128;
  const int E = in_sizes[2] / 64;
  if (E <= 0 || N <= 0) return;

  float* out   = (float*)d_out;
  float* wregN = out + (long long)N * 128;          // E-float region: pose -> final weights
  // d_out node region scratch (overwritten by gather at the end):
  ux4*   Wf    = (ux4*)d_out;                       // 48KB of W fragments
  int*   eidx  = (int*)((char*)d_out + 65536);      // E*4 = 2MB (node region is 16MB)

  char* wsb = (char*)d_ws;
  unsigned* msgp   = (unsigned*)wsb;                                  // E*256 B
  float*    scoreS = (float*)(wsb + (size_t)E * 256);                 // E*4
  int*      rowptr = (int*)(wsb + (size_t)E * 256 + (size_t)E * 4);   // N*4
  float*    lse    = (float*)(wsb + (size_t)E * 260 + (size_t)N * 4); // N*4
  const size_t need = (size_t)E * 260 + (size_t)N * 8;
  if (ws_size < need) return;
  if ((size_t)out_size < (size_t)N * 128 + (size_t)E) return;
  if ((size_t)N * 128 * 4 < 65536 + (size_t)E * 4) return;  // node region must hold Wf+eidx

  (void)hipMemsetAsync(rowptr, 0, (size_t)N * 4, stream);
  k_prep<<<12, 256, 0, stream>>>(W1, W2, Wf);
  k_hist<<<1024, 256, 0, stream>>>(ei, rowptr, E);
  k_scan<<<1, 1024, 0, stream>>>(rowptr, N);
  k_fill<<<1024, 256, 0, stream>>>(ei, rowptr, (int*)wregN, eidx, E);
  k1_fused<<<(E + 127) / 128, 256, 0, stream>>>(x, ei, ea, Wf, b1, b2, attn,
                                                eidx, msgp, scoreS, E);
  k_gather<<<(N + 3) / 4, 256, 0, stream>>>(msgp, scoreS, rowptr, lse, out, N);
  k_wfin<<<1024, 256, 0, stream>>>((int*)wregN, ei, scoreS, lse, E);
}